// Round 19
// baseline (1014.919 us; speedup 1.0000x reference)
//
#include <hip/hip_runtime.h>
#include <math.h>

#define NPTS 4096
#define NBATCH 4
#define BLOCK 512        // 8 waves, 64 rows per block
#define RPW 8            // rows per wave (coords in SGPRs)

static constexpr float KSCALE     = 1.4426950408889634f / 1e-4f;   // log2(e)/eps
static constexpr float INVK2      = 1.0f / (KSCALE * KSCALE);
static constexpr float EPSLN2     = 1e-4f * 0.6931471805599453f;   // eps*ln(2)
static constexpr float NEGEPSLOGW = 8.31776616671934e-4f;          // -eps * (-log(4096))
static constexpr float THR        = 20.0f;   // drop < mu-20: rel mass <= 4096*2^-20

__device__ __forceinline__ float fexp2(float x){
#if __has_builtin(__builtin_amdgcn_exp2f)
  return __builtin_amdgcn_exp2f(x);
#else
  return exp2f(x);
#endif
}
__device__ __forceinline__ float flog2(float x){
#if __has_builtin(__builtin_amdgcn_logf)
  return __builtin_amdgcn_logf(x);
#else
  return log2f(x);
#endif
}
__device__ __forceinline__ float frl(float x){
  return __int_as_float(__builtin_amdgcn_readfirstlane(__float_as_int(x)));
}

// R11 optimum (best measured: 1013 us total, ~22.5 us/softmin dispatch;
// reproduced twice). Two-pass softmin, LDS-staged columns + hierarchical
// skip vote. One launch = two problems (256 blocks each). Block = 512 thr
// = 8 waves, 64 rows/block; wave owns 8 rows (coords in SGPRs). 64 KB pack
// staged to LDS once; both passes read lane-distinct ds_read_b128
// (conflict-free). Pass A: dots + max3 -> cmax[4 chunks][8 rows]; fold +
// shfl -> exact mu. Pass B: chunk-level vote (1024 cols), then group-level
// vote (256 cols) gates the exp2 block. Votes are exact-max based; dropped
// mass <= 4096*2^-20 -> f error ~4e-7 << 5e-4 threshold.
__global__ __launch_bounds__(BLOCK, 4) void softmin_kernel(
    const float* __restrict__ rowA, int rsA, const float4* __restrict__ pkInA,
    float4* __restrict__ pkOutA, const float* __restrict__ hOldA,
    float* __restrict__ outA, int modeA,
    const float* __restrict__ rowB, int rsB, const float4* __restrict__ pkInB,
    float4* __restrict__ pkOutB, const float* __restrict__ hOldB,
    float* __restrict__ outB, int modeB)
{
  __shared__ float4 qs[NPTS];          // 64 KB

  int bid = blockIdx.x;
  const float* rowp; const float4* pkin; float4* pkout; const float* hold;
  float* outp; int rs, mode;
  if (bid < 256) { rowp=rowA; pkin=pkInA; pkout=pkOutA; hold=hOldA; outp=outA; rs=rsA; mode=modeA; }
  else           { rowp=rowB; pkin=pkInB; pkout=pkOutB; hold=hOldB; outp=outB; rs=rsB; mode=modeB; }
  int lb = bid & 255;
  int b  = lb >> 6;          // batch (64 blocks per batch)
  int rb = lb & 63;          // row-block (64 rows per block)

  int tid = threadIdx.x;
  int lane = tid & 63;
  int wu = __builtin_amdgcn_readfirstlane(tid >> 6);
  int r0 = rb*64 + wu*RPW;
  int ridx0 = b*NPTS + r0;

  // ---- stage the whole column pack into LDS (once) ----
  {
    const float4* src = pkin + b*NPTS;
    #pragma unroll
    for (int i = 0; i < NPTS/BLOCK; ++i)
      qs[i*BLOCK + tid] = src[i*BLOCK + tid];
  }

  // wave-uniform row coords -> SGPRs (overlaps staging latency)
  float sx[RPW], sy[RPW], sz[RPW];
  #pragma unroll
  for (int i = 0; i < RPW; ++i) {
    const float* p = rowp + (size_t)(ridx0 + i) * rs;
    sx[i] = frl(p[0]*KSCALE); sy[i] = frl(p[1]*KSCALE); sz[i] = frl(p[2]*KSCALE);
  }

  __syncthreads();

  // ---- pass A: dots + max3 -> cmax[4][8] ----
  float cmax[4][RPW];
  #pragma unroll
  for (int c = 0; c < 4; ++c)
    #pragma unroll
    for (int r = 0; r < RPW; ++r) cmax[c][r] = -INFINITY;

  #pragma unroll
  for (int c = 0; c < 4; ++c) {
    #pragma unroll
    for (int g = 0; g < 4; ++g) {
      int base = c*1024 + g*256 + lane;
      float4 q0 = qs[base], q1 = qs[base+64], q2 = qs[base+128], q3 = qs[base+192];
      #pragma unroll
      for (int r = 0; r < RPW; ++r) {
        float t0 = fmaf(sx[r],q0.x,fmaf(sy[r],q0.y,fmaf(sz[r],q0.z,q0.w)));
        float t1 = fmaf(sx[r],q1.x,fmaf(sy[r],q1.y,fmaf(sz[r],q1.z,q1.w)));
        float t2 = fmaf(sx[r],q2.x,fmaf(sy[r],q2.y,fmaf(sz[r],q2.z,q2.w)));
        float t3 = fmaf(sx[r],q3.x,fmaf(sy[r],q3.y,fmaf(sz[r],q3.z,q3.w)));
        float u  = fmaxf(fmaxf(t0,t1),t2);          // v_max3
        cmax[c][r] = fmaxf(fmaxf(u,t3),cmax[c][r]); // v_max3
      }
    }
  }

  // exact global max per row
  float M[RPW];
  #pragma unroll
  for (int r = 0; r < RPW; ++r) {
    float mm = fmaxf(fmaxf(cmax[0][r],cmax[1][r]), fmaxf(cmax[2][r],cmax[3][r]));
    #pragma unroll
    for (int off = 32; off; off >>= 1) mm = fmaxf(mm, __shfl_xor(mm, off, 64));
    M[r] = mm;
  }

  // ---- pass B: exp2 only where it can contribute (hierarchical vote) ----
  float S[RPW];
  #pragma unroll
  for (int r = 0; r < RPW; ++r) S[r] = 0.f;

  #pragma unroll
  for (int c = 0; c < 4; ++c) {
    int am = 0;
    #pragma unroll
    for (int r = 0; r < RPW; ++r)
      am |= __any(cmax[c][r] > M[r] - THR) ? (1 << r) : 0;
    if (am) {
      #pragma unroll
      for (int g = 0; g < 4; ++g) {
        int base = c*1024 + g*256 + lane;
        float4 q0 = qs[base], q1 = qs[base+64], q2 = qs[base+128], q3 = qs[base+192];
        #pragma unroll
        for (int r = 0; r < RPW; ++r) if (am & (1 << r)) {
          float t0 = fmaf(sx[r],q0.x,fmaf(sy[r],q0.y,fmaf(sz[r],q0.z,q0.w)));
          float t1 = fmaf(sx[r],q1.x,fmaf(sy[r],q1.y,fmaf(sz[r],q1.z,q1.w)));
          float t2 = fmaf(sx[r],q2.x,fmaf(sy[r],q2.y,fmaf(sz[r],q2.z,q2.w)));
          float t3 = fmaf(sx[r],q3.x,fmaf(sy[r],q3.y,fmaf(sz[r],q3.z,q3.w)));
          float u  = fmaxf(fmaxf(t0,t1),t2);
          float v  = fmaxf(u,t3);
          if (__any(v > M[r] - THR)) {     // group-level refine (256 cols)
            float e0 = fexp2(t0-M[r]) + fexp2(t1-M[r]);
            float e1 = fexp2(t2-M[r]) + fexp2(t3-M[r]);
            S[r] += e0 + e1;
          }
        }
      }
    }
  }

  // ---- merge + write ----
  #pragma unroll
  for (int r = 0; r < RPW; ++r) {
    float s = S[r];
    #pragma unroll
    for (int off = 32; off; off >>= 1) s += __shfl_xor(s, off, 64);
    float ch = 0.5f*(sx[r]*sx[r] + sy[r]*sy[r] + sz[r]*sz[r]) * INVK2;
    float res = fmaf(-EPSLN2, M[r] + flog2(s), ch + NEGEPSLOGW);
    if (lane == r) {
      if (mode) res = 0.5f*(hold[ridx0 + r] + res);
      outp[ridx0 + r] = res;
      ((float*)(pkout + (ridx0 + r)))[3] = (res - ch) * KSCALE;
    }
  }
}

// Build the 6 packed column arrays once per launch. .w gets the h=0 initial Atilde.
__global__ void pack_init(const float* __restrict__ x, const float* __restrict__ y,
                          float4* pkfab, float4* pkgab,
                          float4* pkfaa0, float4* pkfaa1,
                          float4* pkgbb0, float4* pkgbb1)
{
  int i = blockIdx.x*256 + threadIdx.x;        // 0..16383 == b*4096+m
  const float* xp = x + (size_t)i*3;
  float xx = xp[0], xy = xp[1], xz = xp[2];
  float4 vx; vx.x=xx; vx.y=xy; vx.z=xz;
  vx.w = -0.5f*(xx*xx + xy*xy + xz*xz)*KSCALE;
  const float* yp = y + (size_t)i*4;
  float yx = yp[0], yy = yp[1], yz = yp[2];
  float4 vy; vy.x=yx; vy.y=yy; vy.z=yz;
  vy.w = -0.5f*(yx*yx + yy*yy + yz*yz)*KSCALE;
  pkgab[i]  = vx; pkfaa0[i] = vx; pkfaa1[i] = vx;
  pkfab[i]  = vy; pkgbb0[i] = vy; pkgbb1[i] = vy;
}

__global__ void reduce_kernel(const float* __restrict__ fab, const float* __restrict__ faa,
                              const float* __restrict__ gab, const float* __restrict__ gbb,
                              float* __restrict__ out)
{
  int b = blockIdx.x;
  int tid = threadIdx.x;
  float s = 0.f;
  for (int i = tid; i < NPTS; i += 256) {
    int idx = b*NPTS + i;
    s += (fab[idx] - faa[idx]) + (gab[idx] - gbb[idx]);
  }
  for (int off = 32; off > 0; off >>= 1) s += __shfl_down(s, off, 64);
  __shared__ float red[4];
  if ((tid & 63) == 0) red[tid >> 6] = s;
  __syncthreads();
  if (tid == 0) out[b] = (red[0]+red[1]+red[2]+red[3]) * (1.0f/NPTS);
}

extern "C" void kernel_launch(void* const* d_in, const int* in_sizes, int n_in,
                              void* d_out, int out_size, void* d_ws, size_t ws_size,
                              hipStream_t stream)
{
  const float* x = (const float*)d_in[0];   // (4,4096,3)
  const float* y = (const float*)d_in[1];   // (4,4096,4), first 3 comps used
  float* ws = (float*)d_ws;
  const size_t P = (size_t)NBATCH * NPTS;   // 16384

  float* f_ab    = ws + 0*P;
  float* g_ab    = ws + 1*P;
  float* faaR[2] = { ws + 2*P, ws + 4*P };
  float* gbbR[2] = { ws + 3*P, ws + 5*P };
  float4* pk4    = (float4*)(ws + 6*P);
  float4* PKfab    = pk4 + 0*P;             // cols = y, .w = Atilde(g_ab)
  float4* PKgab    = pk4 + 1*P;             // cols = x, .w = Atilde(f_ab)
  float4* PKfaa[2] = { pk4 + 2*P, pk4 + 3*P };
  float4* PKgbb[2] = { pk4 + 4*P, pk4 + 5*P };

  // zero h_old for the first averaged symmetric step (faaR[0], gbbR[0] contiguous)
  hipMemsetAsync(ws + 2*P, 0, 2*P*sizeof(float), stream);
  pack_init<<<dim3(P/256), dim3(256), 0, stream>>>(x, y, PKfab, PKgab,
                                                   PKfaa[0], PKfaa[1], PKgbb[0], PKgbb[1]);

  for (int i = 0; i < 21; ++i) {
    int cur = i & 1, nxt = cur ^ 1;
    int modeS = (i < 20) ? 1 : 0;    // averaged symmetric update except final softmin
    // phase 1: f_ab = softmin over y-cols (Atilde from g_ab)  ||  f_aa step
    softmin_kernel<<<512, BLOCK, 0, stream>>>(
        x, 3, PKfab, PKgab, f_ab, f_ab, 0,
        x, 3, PKfaa[cur], PKfaa[nxt], faaR[cur], faaR[nxt], modeS);
    // phase 2: g_ab = softmin over x-cols (Atilde from f_ab)  ||  g_bb step
    softmin_kernel<<<512, BLOCK, 0, stream>>>(
        y, 4, PKgab, PKfab, g_ab, g_ab, 0,
        y, 4, PKgbb[cur], PKgbb[nxt], gbbR[cur], gbbR[nxt], modeS);
  }
  // i=20 wrote faaR[1]/gbbR[1]
  reduce_kernel<<<dim3(4), dim3(256), 0, stream>>>(f_ab, faaR[1], g_ab, gbbR[1], (float*)d_out);
}

// Round 20
// 910.163 us; speedup vs baseline: 1.1151x; 1.1151x over previous
//
#include <hip/hip_runtime.h>
#include <math.h>

#define NPTS 4096
#define NBATCH 4
#define BLOCK 512        // 8 waves, 64 rows per block
#define RPW 8            // rows per wave (coords in SGPRs)

static constexpr float KSCALE     = 1.4426950408889634f / 1e-4f;   // log2(e)/eps
static constexpr float INVK2      = 1.0f / (KSCALE * KSCALE);
static constexpr float EPSLN2     = 1e-4f * 0.6931471805599453f;   // eps*ln(2)
static constexpr float NEGEPSLOGW = 8.31776616671934e-4f;          // -eps * (-log(4096))
static constexpr float THR        = 20.0f;   // drop < max-20: rel mass <= 4096*2^-20

__device__ __forceinline__ float fexp2(float x){
#if __has_builtin(__builtin_amdgcn_exp2f)
  return __builtin_amdgcn_exp2f(x);
#else
  return exp2f(x);
#endif
}
__device__ __forceinline__ float flog2(float x){
#if __has_builtin(__builtin_amdgcn_logf)
  return __builtin_amdgcn_logf(x);
#else
  return log2f(x);
#endif
}
__device__ __forceinline__ float frl(float x){
  return __int_as_float(__builtin_amdgcn_readfirstlane(__float_as_int(x)));
}

// Hybrid softmin. One launch = two problems:
//  A-side (bid<256, CROSS chains f_ab/g_ab): R11 two-pass body verbatim
//    (pass A dots+max3 -> cmax[4][8]; exact mu; pass B hierarchical vote).
//  B-side (bid>=256, SYMMETRIC chains faa/gbb, rows==cols): single-pass
//    online LSE warm-started at the DIAGONAL bound
//      M_init[r] = (h[r] + 0.5|p_r|^2)*KSCALE = t_{j=r}  (C(p,p)=0),
//    an exact member of the score set -> sound lower bound on the row max.
//    Votes are effective immediately (~1-2 of 16 groups active); the
//    diagonal's own group always passes (cmax >= M_init) so S>0 (no
//    log2(0) -- the R17 failure is structurally excluded). M grows
//    monotonically from a true lower bound, so every skipped score is
//    < M_final - THR: identical mass guarantee to two-pass (<= 4096*2^-20).
__global__ __launch_bounds__(BLOCK, 4) void softmin_kernel(
    const float* __restrict__ rowA, int rsA, const float4* __restrict__ pkInA,
    float4* __restrict__ pkOutA, const float* __restrict__ hOldA,
    float* __restrict__ outA, int modeA,
    const float* __restrict__ rowB, int rsB, const float4* __restrict__ pkInB,
    float4* __restrict__ pkOutB, const float* __restrict__ hOldB,
    float* __restrict__ outB, int modeB)
{
  __shared__ float4 qs[NPTS];          // 64 KB

  int bid = blockIdx.x;
  const float* rowp; const float4* pkin; float4* pkout; const float* hold;
  float* outp; int rs, mode;
  if (bid < 256) { rowp=rowA; pkin=pkInA; pkout=pkOutA; hold=hOldA; outp=outA; rs=rsA; mode=modeA; }
  else           { rowp=rowB; pkin=pkInB; pkout=pkOutB; hold=hOldB; outp=outB; rs=rsB; mode=modeB; }
  int lb = bid & 255;
  int b  = lb >> 6;          // batch (64 blocks per batch)
  int rb = lb & 63;          // row-block (64 rows per block)

  int tid = threadIdx.x;
  int lane = tid & 63;
  int wu = __builtin_amdgcn_readfirstlane(tid >> 6);
  int r0 = rb*64 + wu*RPW;
  int ridx0 = b*NPTS + r0;

  // ---- stage the whole column pack into LDS (once) ----
  {
    const float4* src = pkin + b*NPTS;
    #pragma unroll
    for (int i = 0; i < NPTS/BLOCK; ++i)
      qs[i*BLOCK + tid] = src[i*BLOCK + tid];
  }

  // wave-uniform row coords (+ h for the averaged update) -> SGPRs
  float sx[RPW], sy[RPW], sz[RPW], hh[RPW];
  #pragma unroll
  for (int i = 0; i < RPW; ++i) {
    const float* p = rowp + (size_t)(ridx0 + i) * rs;
    sx[i] = frl(p[0]*KSCALE); sy[i] = frl(p[1]*KSCALE); sz[i] = frl(p[2]*KSCALE);
    hh[i] = frl(hold[ridx0 + i]);
  }

  __syncthreads();

  if (bid < 256) {
    // ================= A-side: two-pass (cross chains) =================
    float cmax[4][RPW];
    #pragma unroll
    for (int c = 0; c < 4; ++c)
      #pragma unroll
      for (int r = 0; r < RPW; ++r) cmax[c][r] = -INFINITY;

    #pragma unroll
    for (int c = 0; c < 4; ++c) {
      #pragma unroll
      for (int g = 0; g < 4; ++g) {
        int base = c*1024 + g*256 + lane;
        float4 q0 = qs[base], q1 = qs[base+64], q2 = qs[base+128], q3 = qs[base+192];
        #pragma unroll
        for (int r = 0; r < RPW; ++r) {
          float t0 = fmaf(sx[r],q0.x,fmaf(sy[r],q0.y,fmaf(sz[r],q0.z,q0.w)));
          float t1 = fmaf(sx[r],q1.x,fmaf(sy[r],q1.y,fmaf(sz[r],q1.z,q1.w)));
          float t2 = fmaf(sx[r],q2.x,fmaf(sy[r],q2.y,fmaf(sz[r],q2.z,q2.w)));
          float t3 = fmaf(sx[r],q3.x,fmaf(sy[r],q3.y,fmaf(sz[r],q3.z,q3.w)));
          float u  = fmaxf(fmaxf(t0,t1),t2);          // v_max3
          cmax[c][r] = fmaxf(fmaxf(u,t3),cmax[c][r]); // v_max3
        }
      }
    }

    float M[RPW];
    #pragma unroll
    for (int r = 0; r < RPW; ++r) {
      float mm = fmaxf(fmaxf(cmax[0][r],cmax[1][r]), fmaxf(cmax[2][r],cmax[3][r]));
      #pragma unroll
      for (int off = 32; off; off >>= 1) mm = fmaxf(mm, __shfl_xor(mm, off, 64));
      M[r] = mm;
    }

    float S[RPW];
    #pragma unroll
    for (int r = 0; r < RPW; ++r) S[r] = 0.f;

    #pragma unroll
    for (int c = 0; c < 4; ++c) {
      int am = 0;
      #pragma unroll
      for (int r = 0; r < RPW; ++r)
        am |= __any(cmax[c][r] > M[r] - THR) ? (1 << r) : 0;
      if (am) {
        #pragma unroll
        for (int g = 0; g < 4; ++g) {
          int base = c*1024 + g*256 + lane;
          float4 q0 = qs[base], q1 = qs[base+64], q2 = qs[base+128], q3 = qs[base+192];
          #pragma unroll
          for (int r = 0; r < RPW; ++r) if (am & (1 << r)) {
            float t0 = fmaf(sx[r],q0.x,fmaf(sy[r],q0.y,fmaf(sz[r],q0.z,q0.w)));
            float t1 = fmaf(sx[r],q1.x,fmaf(sy[r],q1.y,fmaf(sz[r],q1.z,q1.w)));
            float t2 = fmaf(sx[r],q2.x,fmaf(sy[r],q2.y,fmaf(sz[r],q2.z,q2.w)));
            float t3 = fmaf(sx[r],q3.x,fmaf(sy[r],q3.y,fmaf(sz[r],q3.z,q3.w)));
            float u  = fmaxf(fmaxf(t0,t1),t2);
            float v  = fmaxf(u,t3);
            if (__any(v > M[r] - THR)) {     // group-level refine (256 cols)
              float e0 = fexp2(t0-M[r]) + fexp2(t1-M[r]);
              float e1 = fexp2(t2-M[r]) + fexp2(t3-M[r]);
              S[r] += e0 + e1;
            }
          }
        }
      }
    }

    #pragma unroll
    for (int r = 0; r < RPW; ++r) {
      float s = S[r];
      #pragma unroll
      for (int off = 32; off; off >>= 1) s += __shfl_xor(s, off, 64);
      float ch = 0.5f*(sx[r]*sx[r] + sy[r]*sy[r] + sz[r]*sz[r]) * INVK2;
      float res = fmaf(-EPSLN2, M[r] + flog2(s), ch + NEGEPSLOGW);
      if (lane == r) {
        if (mode) res = 0.5f*(hh[r] + res);
        outp[ridx0 + r] = res;
        ((float*)(pkout + (ridx0 + r)))[3] = (res - ch) * KSCALE;
      }
    }
  } else {
    // ====== B-side: single-pass online, diagonal warm start (symmetric) ======
    float M[RPW], S[RPW], chv[RPW];
    #pragma unroll
    for (int r = 0; r < RPW; ++r) {
      chv[r] = 0.5f*(sx[r]*sx[r] + sy[r]*sy[r] + sz[r]*sz[r]) * INVK2;
      M[r] = (hh[r] + chv[r]) * KSCALE;    // t at the diagonal column (C=0)
      S[r] = 0.f;
    }

    #pragma unroll
    for (int g = 0; g < 16; ++g) {
      int base = g*256 + lane;
      float4 q0 = qs[base], q1 = qs[base+64], q2 = qs[base+128], q3 = qs[base+192];
      #pragma unroll
      for (int r = 0; r < RPW; ++r) {
        float t0 = fmaf(sx[r],q0.x,fmaf(sy[r],q0.y,fmaf(sz[r],q0.z,q0.w)));
        float t1 = fmaf(sx[r],q1.x,fmaf(sy[r],q1.y,fmaf(sz[r],q1.z,q1.w)));
        float t2 = fmaf(sx[r],q2.x,fmaf(sy[r],q2.y,fmaf(sz[r],q2.z,q2.w)));
        float t3 = fmaf(sx[r],q3.x,fmaf(sy[r],q3.y,fmaf(sz[r],q3.z,q3.w)));
        float u    = fmaxf(fmaxf(t0,t1),t2);      // v_max3
        float cmax = fmaxf(u,t3);
        if (__any(cmax > M[r] - THR)) {
          float Mn = fmaxf(M[r], cmax);
          float sc = fexp2(M[r] - Mn);
          float e0 = fexp2(t0-Mn) + fexp2(t1-Mn);
          float e1 = fexp2(t2-Mn) + fexp2(t3-Mn);
          S[r] = fmaf(S[r], sc, e0 + e1);
          M[r] = Mn;
        }
      }
    }

    #pragma unroll
    for (int r = 0; r < RPW; ++r) {
      float mm = M[r];
      #pragma unroll
      for (int off = 32; off; off >>= 1) mm = fmaxf(mm, __shfl_xor(mm, off, 64));
      float s = S[r] * fexp2(M[r] - mm);
      #pragma unroll
      for (int off = 32; off; off >>= 1) s += __shfl_xor(s, off, 64);
      float res = fmaf(-EPSLN2, mm + flog2(s), chv[r] + NEGEPSLOGW);
      if (lane == r) {
        if (mode) res = 0.5f*(hh[r] + res);
        outp[ridx0 + r] = res;
        ((float*)(pkout + (ridx0 + r)))[3] = (res - chv[r]) * KSCALE;
      }
    }
  }
}

// Build the 6 packed column arrays once per launch. .w gets the h=0 initial Atilde.
__global__ void pack_init(const float* __restrict__ x, const float* __restrict__ y,
                          float4* pkfab, float4* pkgab,
                          float4* pkfaa0, float4* pkfaa1,
                          float4* pkgbb0, float4* pkgbb1)
{
  int i = blockIdx.x*256 + threadIdx.x;        // 0..16383 == b*4096+m
  const float* xp = x + (size_t)i*3;
  float xx = xp[0], xy = xp[1], xz = xp[2];
  float4 vx; vx.x=xx; vx.y=xy; vx.z=xz;
  vx.w = -0.5f*(xx*xx + xy*xy + xz*xz)*KSCALE;
  const float* yp = y + (size_t)i*4;
  float yx = yp[0], yy = yp[1], yz = yp[2];
  float4 vy; vy.x=yx; vy.y=yy; vy.z=yz;
  vy.w = -0.5f*(yx*yx + yy*yy + yz*yz)*KSCALE;
  pkgab[i]  = vx; pkfaa0[i] = vx; pkfaa1[i] = vx;
  pkfab[i]  = vy; pkgbb0[i] = vy; pkgbb1[i] = vy;
}

__global__ void reduce_kernel(const float* __restrict__ fab, const float* __restrict__ faa,
                              const float* __restrict__ gab, const float* __restrict__ gbb,
                              float* __restrict__ out)
{
  int b = blockIdx.x;
  int tid = threadIdx.x;
  float s = 0.f;
  for (int i = tid; i < NPTS; i += 256) {
    int idx = b*NPTS + i;
    s += (fab[idx] - faa[idx]) + (gab[idx] - gbb[idx]);
  }
  for (int off = 32; off > 0; off >>= 1) s += __shfl_down(s, off, 64);
  __shared__ float red[4];
  if ((tid & 63) == 0) red[tid >> 6] = s;
  __syncthreads();
  if (tid == 0) out[b] = (red[0]+red[1]+red[2]+red[3]) * (1.0f/NPTS);
}

extern "C" void kernel_launch(void* const* d_in, const int* in_sizes, int n_in,
                              void* d_out, int out_size, void* d_ws, size_t ws_size,
                              hipStream_t stream)
{
  const float* x = (const float*)d_in[0];   // (4,4096,3)
  const float* y = (const float*)d_in[1];   // (4,4096,4), first 3 comps used
  float* ws = (float*)d_ws;
  const size_t P = (size_t)NBATCH * NPTS;   // 16384

  float* f_ab    = ws + 0*P;
  float* g_ab    = ws + 1*P;
  float* faaR[2] = { ws + 2*P, ws + 4*P };
  float* gbbR[2] = { ws + 3*P, ws + 5*P };
  float4* pk4    = (float4*)(ws + 6*P);
  float4* PKfab    = pk4 + 0*P;             // cols = y, .w = Atilde(g_ab)
  float4* PKgab    = pk4 + 1*P;             // cols = x, .w = Atilde(f_ab)
  float4* PKfaa[2] = { pk4 + 2*P, pk4 + 3*P };
  float4* PKgbb[2] = { pk4 + 4*P, pk4 + 5*P };

  // zero h_old for the first averaged symmetric step (faaR[0], gbbR[0] contiguous)
  hipMemsetAsync(ws + 2*P, 0, 2*P*sizeof(float), stream);
  pack_init<<<dim3(P/256), dim3(256), 0, stream>>>(x, y, PKfab, PKgab,
                                                   PKfaa[0], PKfaa[1], PKgbb[0], PKgbb[1]);

  for (int i = 0; i < 21; ++i) {
    int cur = i & 1, nxt = cur ^ 1;
    int modeS = (i < 20) ? 1 : 0;    // averaged symmetric update except final softmin
    // phase 1: f_ab = softmin over y-cols (Atilde from g_ab)  ||  f_aa step
    softmin_kernel<<<512, BLOCK, 0, stream>>>(
        x, 3, PKfab, PKgab, f_ab, f_ab, 0,
        x, 3, PKfaa[cur], PKfaa[nxt], faaR[cur], faaR[nxt], modeS);
    // phase 2: g_ab = softmin over x-cols (Atilde from f_ab)  ||  g_bb step
    softmin_kernel<<<512, BLOCK, 0, stream>>>(
        y, 4, PKgab, PKfab, g_ab, g_ab, 0,
        y, 4, PKgbb[cur], PKgbb[nxt], gbbR[cur], gbbR[nxt], modeS);
  }
  // i=20 wrote faaR[1]/gbbR[1]
  reduce_kernel<<<dim3(4), dim3(256), 0, stream>>>(f_ab, faaR[1], g_ab, gbbR[1], (float*)d_out);
}